// Round 3
// baseline (414.984 us; speedup 1.0000x reference)
//
#include <hip/hip_runtime.h>
#include <math.h>

typedef __attribute__((ext_vector_type(8))) short bf16x8;   // 8 bf16 = 4 VGPRs
typedef __attribute__((ext_vector_type(4))) float f32x4;

__device__ __forceinline__ short f2bf(float f) {
    unsigned u = __builtin_bit_cast(unsigned, f);
    u += 0x7fffu + ((u >> 16) & 1u);
    return (short)(u >> 16);
}

// async 16B/lane global->LDS; LDS dest = uniform base + lane*16
__device__ __forceinline__ void cp16(const float* g, float* l) {
    __builtin_amdgcn_global_load_lds((const __attribute__((address_space(1))) void*)g,
                                     (__attribute__((address_space(3))) void*)l, 16, 0, 0);
}

#define TPB 256
#define NBLK 512   // 512 blocks * 4 waves = 2048 waves; 2 blocks/CU (64KB LDS each)

// waitcnt immediates (gfx9 encoding): [3:0]=vm_lo [6:4]=exp [11:8]=lgkm [15:14]=vm_hi
#define WAIT_VM8  0x0F78   // vmcnt(8),  lgkm/exp unrestricted
#define WAIT_VM0  0x0F70   // vmcnt(0)
#define WAIT_LGKM0 0xC07F  // lgkmcnt(0), vm/exp unrestricted

__global__ __launch_bounds__(TPB) void hybrid_qnn_kernel(
    const float* __restrict__ x,        // [nrows, 256]
    const float* __restrict__ enc_w,    // [8, 256]
    const float* __restrict__ enc_b,    // [8]
    const float* __restrict__ rand_p,   // [30]
    const float* __restrict__ head_w,   // [4]
    const float* __restrict__ head_b,   // [1]
    float* __restrict__ out,            // [nrows]
    int nrows)
{
    __shared__ float lds[TPB / 64][2][2048];   // 64 KB

    const int lane = threadIdx.x & 63;
    const int wid  = threadIdx.x >> 6;
    const int gwave  = blockIdx.x * (TPB / 64) + wid;
    const int nwaves = NBLK * (TPB / 64);
    const int col  = lane & 15;
    const int quad = lane >> 4;

    // ---------- fold RandomLayer + head into per-wire (CZ,CX,CY) ----------
    const int w = lane & 3;
    float u00r = 1.f, u00i = 0.f, u01r = 0.f, u01i = 0.f;
    float u10r = 0.f, u10i = 0.f, u11r = 1.f, u11i = 0.f;
    #pragma unroll
    for (int i = 0; i < 8; ++i) {
        int k = w + 4 * i;
        if (k < 30) {
            float th = rand_p[k];
            float s, c;
            __sincosf(0.5f * th, &s, &c);
            int g = k % 3;
            float g00r, g00i, g01r, g01i, g10r, g10i, g11r, g11i;
            if (g == 0)      { g00r = c; g00i = 0.f; g01r = 0.f; g01i = -s;
                               g10r = 0.f; g10i = -s; g11r = c; g11i = 0.f; }
            else if (g == 1) { g00r = c; g00i = 0.f; g01r = -s; g01i = 0.f;
                               g10r = s; g10i = 0.f; g11r = c; g11i = 0.f; }
            else             { g00r = c; g00i = -s; g01r = 0.f; g01i = 0.f;
                               g10r = 0.f; g10i = 0.f; g11r = c; g11i = s; }
            float n00r = g00r*u00r - g00i*u00i + g01r*u10r - g01i*u10i;
            float n00i = g00r*u00i + g00i*u00r + g01r*u10i + g01i*u10r;
            float n01r = g00r*u01r - g00i*u01i + g01r*u11r - g01i*u11i;
            float n01i = g00r*u01i + g00i*u01r + g01r*u11i + g01i*u11r;
            float n10r = g10r*u00r - g10i*u00i + g11r*u10r - g11i*u10i;
            float n10i = g10r*u00i + g10i*u00r + g11r*u10i + g11i*u10r;
            float n11r = g10r*u01r - g10i*u01i + g11r*u11r - g11i*u11i;
            float n11i = g10r*u01i + g10i*u01r + g11r*u11i + g11i*u11r;
            u00r = n00r; u00i = n00i; u01r = n01r; u01i = n01i;
            u10r = n10r; u10i = n10i; u11r = n11r; u11i = n11i;
        }
    }
    float mz = (u00r*u00r + u00i*u00i) - (u10r*u10r + u10i*u10i);
    float m01r = (u00r*u01r + u00i*u01i) - (u10r*u11r + u10i*u11i);
    float m01i = (u00r*u01i - u00i*u01r) - (u10r*u11i - u10i*u11r);
    float mx = m01r, my = -m01i;
    float hww = head_w[w];
    float cz_l = hww * mz, cx_l = hww * mx, cy_l = hww * my;
    float CZ[4], CX[4], CY[4];
    #pragma unroll
    for (int ww = 0; ww < 4; ++ww) {
        CZ[ww] = __shfl(cz_l, ww, 64);
        CX[ww] = __shfl(cx_l, ww, 64);
        CY[ww] = __shfl(cy_l, ww, 64);
    }
    const float hb = head_b[0];
    const float EBc = enc_b[col & 7];

    // ---------- B fragments: B[k][n] = enc_w[n][k], n>=8 zero ----------
    bf16x8 bfrag[8];
    #pragma unroll
    for (int s = 0; s < 8; ++s) {
        #pragma unroll
        for (int j = 0; j < 8; ++j) {
            int k = s * 32 + quad * 8 + j;
            float v = (col < 8) ? enc_w[col * 256 + k] : 0.f;
            bfrag[s][j] = f2bf(v);
        }
    }

    // ---------- barrier-free per-wave async pipeline ----------
    const int ntiles = nrows >> 4;
    const int J = (gwave < ntiles) ? ((ntiles - 1 - gwave) / nwaves + 1) : 0;
    const int NH = 2 * J;   // half-tiles (16 rows x 128 k-floats = 8 KB each)

    auto stage = [&](int jj, int hn) {
        const int trow = (gwave + jj * nwaves) * 16;
        const float* gb = x + (size_t)trow * 256 + hn * 128
                            + (lane >> 5) * 256 + (lane & 31) * 4;
        float* lb = &lds[wid][hn][0];
        #pragma unroll
        for (int i = 0; i < 8; ++i)
            cp16(gb + i * 512, lb + i * 256);
    };

    if (NH >= 1) stage(0, 0);
    if (NH >= 2) stage(0, 1);

    for (int j = 0; j < J; ++j) {
        const int trow = (gwave + j * nwaves) * 16;
        f32x4 acc = {0.f, 0.f, 0.f, 0.f};
        #pragma unroll
        for (int h = 0; h < 2; ++h) {
            const int hcur = 2 * j + h;
            if (hcur + 1 < NH) __builtin_amdgcn_s_waitcnt(WAIT_VM8);
            else               __builtin_amdgcn_s_waitcnt(WAIT_VM0);
            const float* lb = &lds[wid][h][0];
            #pragma unroll
            for (int sl = 0; sl < 4; ++sl) {
                const int fidx = (col >> 1) * 256 + (col & 1) * 128 + sl * 32 + quad * 8;
                f32x4 a0 = *(const f32x4*)(lb + fidx);
                f32x4 a1 = *(const f32x4*)(lb + fidx + 4);
                bf16x8 af;
                af[0] = f2bf(a0[0]); af[1] = f2bf(a0[1]);
                af[2] = f2bf(a0[2]); af[3] = f2bf(a0[3]);
                af[4] = f2bf(a1[0]); af[5] = f2bf(a1[1]);
                af[6] = f2bf(a1[2]); af[7] = f2bf(a1[3]);
                acc = __builtin_amdgcn_mfma_f32_16x16x32_bf16(af, bfrag[h * 4 + sl], acc, 0, 0, 0);
            }
            const int hnext = hcur + 2;
            if (hnext < NH) {
                __builtin_amdgcn_s_waitcnt(WAIT_LGKM0);  // ds_reads of this slot done
                stage(hnext >> 1, hnext & 1);
            }
        }
        // ---------- epilogue: shuffle-transpose, no LDS ----------
        float res[4];
        #pragma unroll
        for (int r = 0; r < 4; ++r) {
            float t = tanhf(acc[r] + EBc);
            float sv, cv;
            __sincosf(t, &sv, &cv);
            float psv = __shfl_xor(sv, 4, 64);
            float pcv = __shfl_xor(cv, 4, 64);
            const int ww = col & 3;
            float term = cv * (CZ[ww] * pcv + CX[ww] * psv) - CY[ww] * sv;
            term += __shfl_xor(term, 1, 64);
            term += __shfl_xor(term, 2, 64);
            res[r] = hb + term;
        }
        if (col == 0) {
            f32x4 o = {res[0], res[1], res[2], res[3]};
            *(f32x4*)(out + (size_t)trow + quad * 4) = o;
        }
    }
}

extern "C" void kernel_launch(void* const* d_in, const int* in_sizes, int n_in,
                              void* d_out, int out_size, void* d_ws, size_t ws_size,
                              hipStream_t stream) {
    const float* x  = (const float*)d_in[0];
    const float* ew = (const float*)d_in[1];
    const float* eb = (const float*)d_in[2];
    const float* rp = (const float*)d_in[3];
    const float* hw = (const float*)d_in[4];
    const float* hb = (const float*)d_in[5];
    float* out = (float*)d_out;
    const int nrows = in_sizes[0] / 256;   // 262144
    // MEASUREMENT ROUND: identical kernel launched twice (idempotent output).
    // delta vs R2's dur_us isolates the kernel's true duration, which the
    // rocprof top-5 (all harness fills >= 159us) cannot show.
    hybrid_qnn_kernel<<<NBLK, TPB, 0, stream>>>(x, ew, eb, rp, hw, hb, out, nrows);
    hybrid_qnn_kernel<<<NBLK, TPB, 0, stream>>>(x, ew, eb, rp, hw, hb, out, nrows);
}

// Round 4
// 367.211 us; speedup vs baseline: 1.1301x; 1.1301x over previous
//
#include <hip/hip_runtime.h>
#include <math.h>

typedef __attribute__((ext_vector_type(8))) short bf16x8;   // 8 bf16 = 4 VGPRs
typedef __attribute__((ext_vector_type(4))) float f32x4;

__device__ __forceinline__ short f2bf(float f) {
    unsigned u = __builtin_bit_cast(unsigned, f);
    u += 0x7fffu + ((u >> 16) & 1u);
    return (short)(u >> 16);
}

// async 16B/lane global->LDS; LDS dest = uniform base + lane*16
__device__ __forceinline__ void cp16(const float* g, float* l) {
    __builtin_amdgcn_global_load_lds((const __attribute__((address_space(1))) void*)g,
                                     (__attribute__((address_space(3))) void*)l, 16, 0, 0);
}

#define TPB 256
#define NBLK 512   // 512 blocks * 4 waves = 2048 waves; 2 blocks/CU (64KB LDS each)

// waitcnt immediates (gfx9 encoding): [3:0]=vm_lo [6:4]=exp [11:8]=lgkm [15:14]=vm_hi
#define WAIT_VM8  0x0F78   // vmcnt(8),  lgkm/exp unrestricted
#define WAIT_VM0  0x0F70   // vmcnt(0)
#define WAIT_LGKM0 0xC07F  // lgkmcnt(0), vm/exp unrestricted

// Kernel duration measured via double-launch delta (R3): 46.3 us = 5.82 TB/s
// for 268.4 MB read + 1 MB write -> 92% of the 6.3 TB/s achievable HBM
// ceiling. Memory-roofline-bound; R1's gather variant hits the identical BW.
__global__ __launch_bounds__(TPB) void hybrid_qnn_kernel(
    const float* __restrict__ x,        // [nrows, 256]
    const float* __restrict__ enc_w,    // [8, 256]
    const float* __restrict__ enc_b,    // [8]
    const float* __restrict__ rand_p,   // [30]
    const float* __restrict__ head_w,   // [4]
    const float* __restrict__ head_b,   // [1]
    float* __restrict__ out,            // [nrows]
    int nrows)
{
    __shared__ float lds[TPB / 64][2][2048];   // 64 KB

    const int lane = threadIdx.x & 63;
    const int wid  = threadIdx.x >> 6;
    const int gwave  = blockIdx.x * (TPB / 64) + wid;
    const int nwaves = NBLK * (TPB / 64);
    const int col  = lane & 15;
    const int quad = lane >> 4;

    // ---------- fold RandomLayer + head into per-wire (CZ,CX,CY) ----------
    const int w = lane & 3;
    float u00r = 1.f, u00i = 0.f, u01r = 0.f, u01i = 0.f;
    float u10r = 0.f, u10i = 0.f, u11r = 1.f, u11i = 0.f;
    #pragma unroll
    for (int i = 0; i < 8; ++i) {
        int k = w + 4 * i;
        if (k < 30) {
            float th = rand_p[k];
            float s, c;
            __sincosf(0.5f * th, &s, &c);
            int g = k % 3;
            float g00r, g00i, g01r, g01i, g10r, g10i, g11r, g11i;
            if (g == 0)      { g00r = c; g00i = 0.f; g01r = 0.f; g01i = -s;
                               g10r = 0.f; g10i = -s; g11r = c; g11i = 0.f; }
            else if (g == 1) { g00r = c; g00i = 0.f; g01r = -s; g01i = 0.f;
                               g10r = s; g10i = 0.f; g11r = c; g11i = 0.f; }
            else             { g00r = c; g00i = -s; g01r = 0.f; g01i = 0.f;
                               g10r = 0.f; g10i = 0.f; g11r = c; g11i = s; }
            float n00r = g00r*u00r - g00i*u00i + g01r*u10r - g01i*u10i;
            float n00i = g00r*u00i + g00i*u00r + g01r*u10i + g01i*u10r;
            float n01r = g00r*u01r - g00i*u01i + g01r*u11r - g01i*u11i;
            float n01i = g00r*u01i + g00i*u01r + g01r*u11i + g01i*u11r;
            float n10r = g10r*u00r - g10i*u00i + g11r*u10r - g11i*u10i;
            float n10i = g10r*u00i + g10i*u00r + g11r*u10i + g11i*u10r;
            float n11r = g10r*u01r - g10i*u01i + g11r*u11r - g11i*u11i;
            float n11i = g10r*u01i + g10i*u01r + g11r*u11i + g11i*u11r;
            u00r = n00r; u00i = n00i; u01r = n01r; u01i = n01i;
            u10r = n10r; u10i = n10i; u11r = n11r; u11i = n11i;
        }
    }
    float mz = (u00r*u00r + u00i*u00i) - (u10r*u10r + u10i*u10i);
    float m01r = (u00r*u01r + u00i*u01i) - (u10r*u11r + u10i*u11i);
    float m01i = (u00r*u01i - u00i*u01r) - (u10r*u11i - u10i*u11r);
    float mx = m01r, my = -m01i;
    float hww = head_w[w];
    float cz_l = hww * mz, cx_l = hww * mx, cy_l = hww * my;
    float CZ[4], CX[4], CY[4];
    #pragma unroll
    for (int ww = 0; ww < 4; ++ww) {
        CZ[ww] = __shfl(cz_l, ww, 64);
        CX[ww] = __shfl(cx_l, ww, 64);
        CY[ww] = __shfl(cy_l, ww, 64);
    }
    const float hb = head_b[0];
    const float EBc = enc_b[col & 7];

    // ---------- B fragments: B[k][n] = enc_w[n][k], n>=8 zero ----------
    bf16x8 bfrag[8];
    #pragma unroll
    for (int s = 0; s < 8; ++s) {
        #pragma unroll
        for (int j = 0; j < 8; ++j) {
            int k = s * 32 + quad * 8 + j;
            float v = (col < 8) ? enc_w[col * 256 + k] : 0.f;
            bfrag[s][j] = f2bf(v);
        }
    }

    // ---------- barrier-free per-wave async pipeline ----------
    const int ntiles = nrows >> 4;
    const int J = (gwave < ntiles) ? ((ntiles - 1 - gwave) / nwaves + 1) : 0;
    const int NH = 2 * J;   // half-tiles (16 rows x 128 k-floats = 8 KB each)

    auto stage = [&](int jj, int hn) {
        const int trow = (gwave + jj * nwaves) * 16;
        const float* gb = x + (size_t)trow * 256 + hn * 128
                            + (lane >> 5) * 256 + (lane & 31) * 4;
        float* lb = &lds[wid][hn][0];
        #pragma unroll
        for (int i = 0; i < 8; ++i)
            cp16(gb + i * 512, lb + i * 256);
    };

    if (NH >= 1) stage(0, 0);
    if (NH >= 2) stage(0, 1);

    for (int j = 0; j < J; ++j) {
        const int trow = (gwave + j * nwaves) * 16;
        f32x4 acc = {0.f, 0.f, 0.f, 0.f};
        #pragma unroll
        for (int h = 0; h < 2; ++h) {
            const int hcur = 2 * j + h;
            if (hcur + 1 < NH) __builtin_amdgcn_s_waitcnt(WAIT_VM8);
            else               __builtin_amdgcn_s_waitcnt(WAIT_VM0);
            const float* lb = &lds[wid][h][0];
            #pragma unroll
            for (int sl = 0; sl < 4; ++sl) {
                const int fidx = (col >> 1) * 256 + (col & 1) * 128 + sl * 32 + quad * 8;
                f32x4 a0 = *(const f32x4*)(lb + fidx);
                f32x4 a1 = *(const f32x4*)(lb + fidx + 4);
                bf16x8 af;
                af[0] = f2bf(a0[0]); af[1] = f2bf(a0[1]);
                af[2] = f2bf(a0[2]); af[3] = f2bf(a0[3]);
                af[4] = f2bf(a1[0]); af[5] = f2bf(a1[1]);
                af[6] = f2bf(a1[2]); af[7] = f2bf(a1[3]);
                acc = __builtin_amdgcn_mfma_f32_16x16x32_bf16(af, bfrag[h * 4 + sl], acc, 0, 0, 0);
            }
            const int hnext = hcur + 2;
            if (hnext < NH) {
                __builtin_amdgcn_s_waitcnt(WAIT_LGKM0);  // ds_reads of this slot done
                stage(hnext >> 1, hnext & 1);
            }
        }
        // ---------- epilogue: shuffle-transpose, no LDS ----------
        float res[4];
        #pragma unroll
        for (int r = 0; r < 4; ++r) {
            float t = tanhf(acc[r] + EBc);
            float sv, cv;
            __sincosf(t, &sv, &cv);
            float psv = __shfl_xor(sv, 4, 64);
            float pcv = __shfl_xor(cv, 4, 64);
            const int ww = col & 3;
            float term = cv * (CZ[ww] * pcv + CX[ww] * psv) - CY[ww] * sv;
            term += __shfl_xor(term, 1, 64);
            term += __shfl_xor(term, 2, 64);
            res[r] = hb + term;
        }
        if (col == 0) {
            f32x4 o = {res[0], res[1], res[2], res[3]};
            *(f32x4*)(out + (size_t)trow + quad * 4) = o;
        }
    }
}

extern "C" void kernel_launch(void* const* d_in, const int* in_sizes, int n_in,
                              void* d_out, int out_size, void* d_ws, size_t ws_size,
                              hipStream_t stream) {
    const float* x  = (const float*)d_in[0];
    const float* ew = (const float*)d_in[1];
    const float* eb = (const float*)d_in[2];
    const float* rp = (const float*)d_in[3];
    const float* hw = (const float*)d_in[4];
    const float* hb = (const float*)d_in[5];
    float* out = (float*)d_out;
    const int nrows = in_sizes[0] / 256;   // 262144
    hybrid_qnn_kernel<<<NBLK, TPB, 0, stream>>>(x, ew, eb, rp, hw, hb, out, nrows);
}